// Round 6
// baseline (4214.903 us; speedup 1.0000x reference)
//
#include <hip/hip_runtime.h>
#include <math.h>

#define TOKENS 16384
#define DIM    7168
#define NEXP   256
#define TK     8
#define BM     32
#define BK     32
#define NKT    (DIM / BK)   /* 224 */
#define DELTA  8.0e-3f      /* candidate margin on f32 logits */
#define MAXC   12

// GEMM LDS (floats): As[2][32][37], Bs[2][32][261]  (strides ≡5 mod 32)
#define AS_OFF(buf)  ((buf) * (32 * 37))
#define BS_OFF(buf)  (2 * 32 * 37 + (buf) * (32 * 261))
#define LDS_FLOATS   (2 * 32 * 37 + 2 * 32 * 261)   /* 19072 */
#define LDS_BYTES    (LDS_FLOATS * 4)                /* 76288 B -> 2 blocks/CU */
// Epilogue overlay (floats): lgf[32][260] at 0; then repair structs:
#define VAL_OFF   8320    /* f64[32][12]  = 768 floats, byte off 33280 (8-aligned) */
#define CAND_OFF  9088    /* int[32][12]  = 384 */
#define CNT_OFF   9472    /* int[32] */
#define M_OFF     9504    /* f32[32] */
#define INVS_OFF  9536    /* f32[32] */

__global__ __launch_bounds__(256, 2)
void gate_f32r(const float* __restrict__ x,
               const float* __restrict__ w,
               float* __restrict__ outw,
               float* __restrict__ outi)
{
    extern __shared__ __align__(16) float smemf[];
    float*  lgf     = smemf;
    double* valLds  = (double*)(smemf + VAL_OFF);
    int*    candLds = (int*)(smemf + CAND_OFF);
    int*    cntLds  = (int*)(smemf + CNT_OFF);
    float*  mArr    = smemf + M_OFF;
    float*  invsArr = smemf + INVS_OFF;

    const int t    = threadIdx.x;
    const int tx   = t & 31;
    const int ty   = t >> 5;
    const int lane = t & 63;
    const int wv   = t >> 6;
    const int tok0 = blockIdx.x * BM;

    const int ldq = t >> 3;
    const int kq  = (t & 7) * 4;

    const float* xp = x + (size_t)(tok0 + ldq) * DIM + kq;
    const float* wp = w + (size_t)ldq * DIM + kq;

    float acc[2][4][4];
    #pragma unroll
    for (int eg = 0; eg < 2; ++eg)
        #pragma unroll
        for (int i = 0; i < 4; ++i)
            #pragma unroll
            for (int j = 0; j < 4; ++j)
                acc[eg][i][j] = 0.0f;

    float4 ar, br0, br1, br2, br3, br4, br5, br6, br7;

#define LOADT(kt) do {                                        \
    const float* xq = xp + (size_t)(kt) * BK;                 \
    ar  = *(const float4*)(xq);                               \
    const float* wq = wp + (size_t)(kt) * BK;                 \
    br0 = *(const float4*)(wq);                               \
    br1 = *(const float4*)(wq + (size_t) 32 * DIM);           \
    br2 = *(const float4*)(wq + (size_t) 64 * DIM);           \
    br3 = *(const float4*)(wq + (size_t) 96 * DIM);           \
    br4 = *(const float4*)(wq + (size_t)128 * DIM);           \
    br5 = *(const float4*)(wq + (size_t)160 * DIM);           \
    br6 = *(const float4*)(wq + (size_t)192 * DIM);           \
    br7 = *(const float4*)(wq + (size_t)224 * DIM);           \
} while (0)

#define STB(Bw, i, v)                                         \
    (Bw)[(kq+0)*261 + ldq + (i)*32] = (v).x;                  \
    (Bw)[(kq+1)*261 + ldq + (i)*32] = (v).y;                  \
    (Bw)[(kq+2)*261 + ldq + (i)*32] = (v).z;                  \
    (Bw)[(kq+3)*261 + ldq + (i)*32] = (v).w;

#define STASH(buf) do {                                       \
    float* Aw = smemf + AS_OFF(buf);                          \
    Aw[(kq+0)*37 + ldq] = ar.x;                               \
    Aw[(kq+1)*37 + ldq] = ar.y;                               \
    Aw[(kq+2)*37 + ldq] = ar.z;                               \
    Aw[(kq+3)*37 + ldq] = ar.w;                               \
    float* Bw = smemf + BS_OFF(buf);                          \
    STB(Bw, 0, br0) STB(Bw, 1, br1) STB(Bw, 2, br2)           \
    STB(Bw, 3, br3) STB(Bw, 4, br4) STB(Bw, 5, br5)           \
    STB(Bw, 6, br6) STB(Bw, 7, br7)                           \
} while (0)

    LOADT(0);
    STASH(0);
    __syncthreads();

    for (int kt = 0; kt < NKT; ++kt) {
        const int cur = kt & 1;
        if (kt + 1 < NKT) LOADT(kt + 1);
        const float* Ac = smemf + AS_OFF(cur);
        const float* Bc = smemf + BS_OFF(cur);
        #pragma unroll 16
        for (int kk = 0; kk < BK; ++kk) {
            float4 a4 = *(const float4*)(Ac + kk * 37 + ty * 4);
            float4 b0 = *(const float4*)(Bc + kk * 261 + tx * 4);
            float4 b1 = *(const float4*)(Bc + kk * 261 + tx * 4 + 128);
            float af[4], b0f[4], b1f[4];
            af[0]=a4.x; af[1]=a4.y; af[2]=a4.z; af[3]=a4.w;
            b0f[0]=b0.x; b0f[1]=b0.y; b0f[2]=b0.z; b0f[3]=b0.w;
            b1f[0]=b1.x; b1f[1]=b1.y; b1f[2]=b1.z; b1f[3]=b1.w;
            #pragma unroll
            for (int i = 0; i < 4; ++i)
                #pragma unroll
                for (int j = 0; j < 4; ++j) {
                    acc[0][i][j] = fmaf(af[i], b0f[j], acc[0][i][j]);
                    acc[1][i][j] = fmaf(af[i], b1f[j], acc[1][i][j]);
                }
        }
        if (kt + 1 < NKT) STASH((kt + 1) & 1);
        __syncthreads();
    }

    // ---- E1: f32 logits to LDS overlay (stride 260) ----
    #pragma unroll
    for (int i = 0; i < 4; ++i) {
        float* lr = lgf + (size_t)(ty * 4 + i) * 260 + tx * 4;
        float4 v0, v1;
        v0.x = acc[0][i][0]; v0.y = acc[0][i][1];
        v0.z = acc[0][i][2]; v0.w = acc[0][i][3];
        v1.x = acc[1][i][0]; v1.y = acc[1][i][1];
        v1.z = acc[1][i][2]; v1.w = acc[1][i][3];
        *(float4*)(lr)       = v0;
        *(float4*)(lr + 128) = v1;
    }
    __syncthreads();

    // ---- E2a: softmax + candidate extraction; wave owns 8 tokens ----
    for (int r8 = 0; r8 < 8; ++r8) {
        const int row = wv * 8 + r8;
        float4 v = *(const float4*)(lgf + (size_t)row * 260 + lane * 4);
        float vv[4] = {v.x, v.y, v.z, v.w};

        float m = fmaxf(fmaxf(vv[0], vv[1]), fmaxf(vv[2], vv[3]));
        #pragma unroll
        for (int off = 32; off >= 1; off >>= 1)
            m = fmaxf(m, __shfl_xor(m, off));

        float s = expf(vv[0] - m) + expf(vv[1] - m)
                + expf(vv[2] - m) + expf(vv[3] - m);
        #pragma unroll
        for (int off = 32; off >= 1; off >>= 1)
            s += __shfl_xor(s, off);

        int   taken = 0;
        int   ncand = 0;
        float s8    = 0.0f;
        int   my_ci = 1 << 30;
        for (int it = 0; it < MAXC; ++it) {
            float bv = -INFINITY;
            int   bi = 1 << 30;
            #pragma unroll
            for (int j = 0; j < 4; ++j) {
                float cv = ((taken >> j) & 1) ? -INFINITY : vv[j];
                int   ci = lane * 4 + j;
                if (cv > bv || (cv == bv && ci < bi)) { bv = cv; bi = ci; }
            }
            #pragma unroll
            for (int off = 32; off >= 1; off >>= 1) {
                float ov = __shfl_xor(bv, off);
                int   oi = __shfl_xor(bi, off);
                if (ov > bv || (ov == bv && oi < bi)) { bv = ov; bi = oi; }
            }
            if (it == 7) s8 = bv;
            if (it >= 8 && bv < s8 - DELTA) break;   // wave-uniform
            if (lane == it) my_ci = bi;
            if ((bi >> 2) == lane) taken |= 1 << (bi & 3);
            ncand = it + 1;
        }

        if (lane < ncand) candLds[row * MAXC + lane] = my_ci;
        if (lane == 0) {
            cntLds[row]  = ncand;
            mArr[row]    = m;
            invsArr[row] = 1.0f / s;
        }
    }
    __syncthreads();

    // ---- E2b: block-cooperative f64 repair (candidate-parallel) ----
    for (int rowi = 0; rowi < BM; ++rowi) {
        const int nc = cntLds[rowi];
        const float* xrow = x + (size_t)(tok0 + rowi) * DIM + lane * 4;
        for (int c = wv; c < nc; c += 4) {
            const int e = candLds[rowi * MAXC + c];
            const float* wrow = w + (size_t)e * DIM + lane * 4;
            double a0 = 0.0, a1 = 0.0, a2 = 0.0, a3 = 0.0;
            #pragma unroll
            for (int j = 0; j < 28; j += 4) {
                float4 x0 = *(const float4*)(xrow + (j+0) * 256);
                float4 q0 = *(const float4*)(wrow + (j+0) * 256);
                float4 x1 = *(const float4*)(xrow + (j+1) * 256);
                float4 q1 = *(const float4*)(wrow + (j+1) * 256);
                float4 x2 = *(const float4*)(xrow + (j+2) * 256);
                float4 q2 = *(const float4*)(wrow + (j+2) * 256);
                float4 x3 = *(const float4*)(xrow + (j+3) * 256);
                float4 q3 = *(const float4*)(wrow + (j+3) * 256);
                a0 = fma((double)x0.x, (double)q0.x, a0);
                a0 = fma((double)x0.y, (double)q0.y, a0);
                a0 = fma((double)x0.z, (double)q0.z, a0);
                a0 = fma((double)x0.w, (double)q0.w, a0);
                a1 = fma((double)x1.x, (double)q1.x, a1);
                a1 = fma((double)x1.y, (double)q1.y, a1);
                a1 = fma((double)x1.z, (double)q1.z, a1);
                a1 = fma((double)x1.w, (double)q1.w, a1);
                a2 = fma((double)x2.x, (double)q2.x, a2);
                a2 = fma((double)x2.y, (double)q2.y, a2);
                a2 = fma((double)x2.z, (double)q2.z, a2);
                a2 = fma((double)x2.w, (double)q2.w, a2);
                a3 = fma((double)x3.x, (double)q3.x, a3);
                a3 = fma((double)x3.y, (double)q3.y, a3);
                a3 = fma((double)x3.z, (double)q3.z, a3);
                a3 = fma((double)x3.w, (double)q3.w, a3);
            }
            double tot = (a0 + a1) + (a2 + a3);
            #pragma unroll
            for (int off = 32; off >= 1; off >>= 1)
                tot += __shfl_xor(tot, off);
            if (lane == 0) valLds[rowi * MAXC + c] = tot;
        }
    }
    __syncthreads();

    // ---- E2c: final exact top-8 per token; wave owns 8 tokens ----
    for (int r8 = 0; r8 < 8; ++r8) {
        const int row  = wv * 8 + r8;
        const int gtok = tok0 + row;
        const int nc   = cntLds[row];
        const float m    = mArr[row];
        const float invs = invsArr[row];

        double ev    = (lane < nc) ? valLds[row * MAXC + lane] : -1.0e300;
        int    my_ci = (lane < nc) ? candLds[row * MAXC + lane] : (1 << 30);

        for (int it = 0; it < TK; ++it) {
            double bv2 = ev;
            int    bi2 = my_ci;
            int    bs2 = lane;
            #pragma unroll
            for (int off = 32; off >= 1; off >>= 1) {
                double ov = __shfl_xor(bv2, off);
                int    oi = __shfl_xor(bi2, off);
                int    os = __shfl_xor(bs2, off);
                if (ov > bv2 || (ov == bv2 && oi < bi2)) {
                    bv2 = ov; bi2 = oi; bs2 = os;
                }
            }
            if (lane == it) {
                outw[(size_t)gtok * TK + it] = expf((float)bv2 - m) * invs;
                outi[(size_t)gtok * TK + it] = (float)bi2;
            }
            if (lane == bs2) ev = -1.0e300;
        }
    }
}

extern "C" void kernel_launch(void* const* d_in, const int* in_sizes, int n_in,
                              void* d_out, int out_size, void* d_ws, size_t ws_size,
                              hipStream_t stream) {
    const float* x = (const float*)d_in[0];
    const float* w = (const float*)d_in[1];
    float* outw = (float*)d_out;
    float* outi = outw + (size_t)TOKENS * TK;
    gate_f32r<<<dim3(TOKENS / BM), dim3(256), LDS_BYTES, stream>>>(x, w, outw, outi);
}

// Round 7
// 2512.125 us; speedup vs baseline: 1.6778x; 1.6778x over previous
//
#include <hip/hip_runtime.h>
#include <math.h>

#define TOKENS 16384
#define DIM    7168
#define NEXP   256
#define TK     8
#define BM     64
#define BK     32
#define NKT    (DIM / BK)   /* 224 */
#define DELTA  8.0e-3f
#define MAXC   12

/* K1 LDS (floats): X[2][64][34] @0 (2176/buf), W[2][256][34] @4352 (8704/buf).
   Stride 34 floats: 8B-aligned rows (b64 ops), bank spacing 2 -> <=2-way (free).
   Epilogue overlay lgf[64][260] = 16640 floats <= 21760. */
#define XOFF(b)      ((b) * 2176)
#define WOFF(b)      (4352 + (b) * 8704)
#define K1_LDS_BYTES (21760 * 4)

/* ws layout (bytes); total ~1.22 MB (assumes ws_size >= 1.25 MB) */
#define WS_CAND 0
#define WS_CNT  (TOKENS * 16 * 4)
#define WS_M    (WS_CNT + TOKENS * 4)
#define WS_INVS (WS_M + TOKENS * 4)

__global__ __launch_bounds__(256, 1)
void gate_gemm(const float* __restrict__ x, const float* __restrict__ w,
               int* __restrict__ wsCand, int* __restrict__ wsCnt,
               float* __restrict__ wsM, float* __restrict__ wsInvs)
{
    extern __shared__ __align__(16) float smem[];
    const int t    = threadIdx.x;
    const int tx   = t & 31;     /* experts tx + 32j, j<8  (strided: bank-clean) */
    const int ty   = t >> 5;     /* tokens  ty + 8i,  i<8 */
    const int lane = t & 63;
    const int wv   = t >> 6;
    const int tok0 = blockIdx.x * BM;

    /* staging maps */
    const int xr = t >> 2;           /* x row 0..63, 4 threads/row */
    const int xc = (t & 3) * 8;      /* 8 floats each */
    const float* xp = x + (size_t)(tok0 + xr) * DIM + xc;
    const float* wp = w + (size_t)t * DIM;   /* one expert row per thread */

    float4 xs0, xs1, wr0, wr1, wr2, wr3, wr4, wr5, wr6, wr7;

#define LOADT(kt) do {                                          \
    const float* xq = xp + (size_t)(kt) * BK;                   \
    xs0 = *(const float4*)(xq);                                 \
    xs1 = *(const float4*)(xq + 4);                             \
    const float* wq = wp + (size_t)(kt) * BK;                   \
    wr0 = *(const float4*)(wq);      wr1 = *(const float4*)(wq + 4);  \
    wr2 = *(const float4*)(wq + 8);  wr3 = *(const float4*)(wq + 12); \
    wr4 = *(const float4*)(wq + 16); wr5 = *(const float4*)(wq + 20); \
    wr6 = *(const float4*)(wq + 24); wr7 = *(const float4*)(wq + 28); \
} while (0)

#define ST2(P, off, v) {                                        \
    float2 lo_; lo_.x = (v).x; lo_.y = (v).y;                   \
    *(float2*)((P) + (off)) = lo_;                              \
    float2 hi_; hi_.x = (v).z; hi_.y = (v).w;                   \
    *(float2*)((P) + (off) + 2) = hi_; }

#define STASH(buf) do {                                         \
    float* Xw = smem + XOFF(buf) + xr * 34 + xc;                \
    ST2(Xw, 0, xs0) ST2(Xw, 4, xs1)                             \
    float* Ww = smem + WOFF(buf) + t * 34;                      \
    ST2(Ww, 0,  wr0) ST2(Ww, 4,  wr1) ST2(Ww, 8,  wr2) ST2(Ww, 12, wr3) \
    ST2(Ww, 16, wr4) ST2(Ww, 20, wr5) ST2(Ww, 24, wr6) ST2(Ww, 28, wr7) \
} while (0)

    float acc[8][8];
    #pragma unroll
    for (int i = 0; i < 8; ++i)
        #pragma unroll
        for (int j = 0; j < 8; ++j)
            acc[i][j] = 0.0f;

    LOADT(0);
    STASH(0);
    __syncthreads();

    for (int kt = 0; kt < NKT; ++kt) {
        const int cur = kt & 1;
        if (kt + 1 < NKT) LOADT(kt + 1);   /* latency hides under ~4600cy compute */
        const float* Xb = smem + XOFF(cur) + ty * 34;
        const float* Wb = smem + WOFF(cur) + tx * 34;
        #pragma unroll 4
        for (int s2 = 0; s2 < 16; ++s2) {   /* 16 k-slabs of 2 */
            float2 xf[8], wf[8];
            #pragma unroll
            for (int i = 0; i < 8; ++i)
                xf[i] = *(const float2*)(Xb + i * 272 + s2 * 2);
            #pragma unroll
            for (int j = 0; j < 8; ++j)
                wf[j] = *(const float2*)(Wb + j * 1088 + s2 * 2);
            #pragma unroll
            for (int i = 0; i < 8; ++i)
                #pragma unroll
                for (int j = 0; j < 8; ++j) {
                    acc[i][j] = fmaf(xf[i].x, wf[j].x, acc[i][j]);
                    acc[i][j] = fmaf(xf[i].y, wf[j].y, acc[i][j]);
                }
        }
        if (kt + 1 < NKT) STASH((kt + 1) & 1);
        __syncthreads();
    }

    /* ---- logits to LDS overlay [64][260] (16B-aligned rows) ---- */
    float* lgf = smem;
    #pragma unroll
    for (int i = 0; i < 8; ++i)
        #pragma unroll
        for (int j = 0; j < 8; ++j)
            lgf[(ty + 8 * i) * 260 + tx + 32 * j] = acc[i][j];
    __syncthreads();

    /* ---- softmax + candidate extraction; each wave owns 16 tokens ---- */
    for (int r16 = 0; r16 < 16; ++r16) {
        const int row  = wv * 16 + r16;
        const int gtok = tok0 + row;
        float4 v = *(const float4*)(lgf + (size_t)row * 260 + lane * 4);
        float vv[4] = {v.x, v.y, v.z, v.w};

        float m = fmaxf(fmaxf(vv[0], vv[1]), fmaxf(vv[2], vv[3]));
        #pragma unroll
        for (int off = 32; off >= 1; off >>= 1)
            m = fmaxf(m, __shfl_xor(m, off));

        float s = expf(vv[0] - m) + expf(vv[1] - m)
                + expf(vv[2] - m) + expf(vv[3] - m);
        #pragma unroll
        for (int off = 32; off >= 1; off >>= 1)
            s += __shfl_xor(s, off);

        int   taken = 0;
        int   ncand = 0;
        float s8    = 0.0f;
        int   my_ci = 1 << 30;
        for (int it = 0; it < MAXC; ++it) {
            float bv = -INFINITY;
            int   bi = 1 << 30;
            #pragma unroll
            for (int j = 0; j < 4; ++j) {
                float cv = ((taken >> j) & 1) ? -INFINITY : vv[j];
                int   ci = lane * 4 + j;
                if (cv > bv || (cv == bv && ci < bi)) { bv = cv; bi = ci; }
            }
            #pragma unroll
            for (int off = 32; off >= 1; off >>= 1) {
                float ov = __shfl_xor(bv, off);
                int   oi = __shfl_xor(bi, off);
                if (ov > bv || (ov == bv && oi < bi)) { bv = ov; bi = oi; }
            }
            if (it == 7) s8 = bv;
            if (it >= 8 && bv < s8 - DELTA) break;   /* wave-uniform */
            if (lane == it) my_ci = bi;
            if ((bi >> 2) == lane) taken |= 1 << (bi & 3);
            ncand = it + 1;
        }

        if (lane < ncand) wsCand[gtok * 16 + lane] = my_ci;
        if (lane == 0) {
            wsCnt[gtok]  = ncand;
            wsM[gtok]    = m;
            wsInvs[gtok] = 1.0f / s;
        }
    }
}

/* K2: one wave per token. x row cached in registers; exact f64 dots with the
   SAME arithmetic order as the round-2..6 passing kernels. No launch-bounds
   register cap -> no spills. */
__global__ void gate_repair(const float* __restrict__ x,
                            const float* __restrict__ w,
                            const int* __restrict__ wsCand,
                            const int* __restrict__ wsCnt,
                            const float* __restrict__ wsM,
                            const float* __restrict__ wsInvs,
                            float* __restrict__ outw,
                            float* __restrict__ outi)
{
    const int lane = threadIdx.x & 63;
    const int wv   = threadIdx.x >> 6;
    const int gtok = blockIdx.x * 4 + wv;

    const int   nc   = wsCnt[gtok];
    const float m    = wsM[gtok];
    const float invs = wsInvs[gtok];
    int my_ci = (lane < nc) ? wsCand[gtok * 16 + lane] : (1 << 30);

    const float* xrow = x + (size_t)gtok * DIM + lane * 4;
    float4 xv[28];
    #pragma unroll
    for (int j = 0; j < 28; ++j)
        xv[j] = *(const float4*)(xrow + j * 256);

    double ev = -1.0e300;
    for (int c = 0; c < nc; ++c) {
        const int e = __shfl(my_ci, c);
        const float* wrow = w + (size_t)e * DIM + lane * 4;
        double a0 = 0.0, a1 = 0.0, a2 = 0.0, a3 = 0.0;
        #pragma unroll
        for (int j = 0; j < 28; j += 4) {
            float4 q0 = *(const float4*)(wrow + (j + 0) * 256);
            float4 q1 = *(const float4*)(wrow + (j + 1) * 256);
            float4 q2 = *(const float4*)(wrow + (j + 2) * 256);
            float4 q3 = *(const float4*)(wrow + (j + 3) * 256);
            a0 = fma((double)xv[j + 0].x, (double)q0.x, a0);
            a0 = fma((double)xv[j + 0].y, (double)q0.y, a0);
            a0 = fma((double)xv[j + 0].z, (double)q0.z, a0);
            a0 = fma((double)xv[j + 0].w, (double)q0.w, a0);
            a1 = fma((double)xv[j + 1].x, (double)q1.x, a1);
            a1 = fma((double)xv[j + 1].y, (double)q1.y, a1);
            a1 = fma((double)xv[j + 1].z, (double)q1.z, a1);
            a1 = fma((double)xv[j + 1].w, (double)q1.w, a1);
            a2 = fma((double)xv[j + 2].x, (double)q2.x, a2);
            a2 = fma((double)xv[j + 2].y, (double)q2.y, a2);
            a2 = fma((double)xv[j + 2].z, (double)q2.z, a2);
            a2 = fma((double)xv[j + 2].w, (double)q2.w, a2);
            a3 = fma((double)xv[j + 3].x, (double)q3.x, a3);
            a3 = fma((double)xv[j + 3].y, (double)q3.y, a3);
            a3 = fma((double)xv[j + 3].z, (double)q3.z, a3);
            a3 = fma((double)xv[j + 3].w, (double)q3.w, a3);
        }
        double tot = (a0 + a1) + (a2 + a3);
        #pragma unroll
        for (int off = 32; off >= 1; off >>= 1)
            tot += __shfl_xor(tot, off);
        if (lane == c) ev = tot;
    }

    for (int it = 0; it < TK; ++it) {
        double bv2 = ev;
        int    bi2 = my_ci;
        int    bs2 = lane;
        #pragma unroll
        for (int off = 32; off >= 1; off >>= 1) {
            double ov = __shfl_xor(bv2, off);
            int    oi = __shfl_xor(bi2, off);
            int    os = __shfl_xor(bs2, off);
            if (ov > bv2 || (ov == bv2 && oi < bi2)) {
                bv2 = ov; bi2 = oi; bs2 = os;
            }
        }
        if (lane == it) {
            outw[(size_t)gtok * TK + it] = expf((float)bv2 - m) * invs;
            outi[(size_t)gtok * TK + it] = (float)bi2;
        }
        if (lane == bs2) ev = -1.0e300;
    }
}

extern "C" void kernel_launch(void* const* d_in, const int* in_sizes, int n_in,
                              void* d_out, int out_size, void* d_ws, size_t ws_size,
                              hipStream_t stream) {
    const float* x = (const float*)d_in[0];
    const float* w = (const float*)d_in[1];
    float* outw = (float*)d_out;
    float* outi = outw + (size_t)TOKENS * TK;
    char* wsb = (char*)d_ws;
    int*   wsCand = (int*)(wsb + WS_CAND);
    int*   wsCnt  = (int*)(wsb + WS_CNT);
    float* wsM    = (float*)(wsb + WS_M);
    float* wsInvs = (float*)(wsb + WS_INVS);

    gate_gemm<<<dim3(TOKENS / BM), dim3(256), K1_LDS_BYTES, stream>>>(
        x, w, wsCand, wsCnt, wsM, wsInvs);
    gate_repair<<<dim3(TOKENS / 4), dim3(256), 0, stream>>>(
        x, w, wsCand, wsCnt, wsM, wsInvs, outw, outi);
}